// Round 1
// baseline (110.982 us; speedup 1.0000x reference)
//
#include <hip/hip_runtime.h>
#include <math.h>

// Problem constants (from setup_inputs): R=4, I=16, N=2048.
#define RDIM 4
#define IDIM 16
#define NPTS 2048
#define THREADS 256
#define CHUNKS 4                          // row-chunks per pass
#define ROWS_PER_BLOCK (NPTS / CHUNKS)    // 512
#define U (ROWS_PER_BLOCK / THREADS)      // 2 rows per thread

__global__ __launch_bounds__(THREADS, 2)
void chamfer_pass(const float* __restrict__ src,   // [4,16,2048,3]
                  const float* __restrict__ tgt,   // [16,2048,3]
                  const float* __restrict__ rotv,  // [4,16,3]
                  const float* __restrict__ trav,  // [4,16,3]
                  const float* __restrict__ scal,  // [4,16]
                  float* __restrict__ out)         // [4,16]
{
    __shared__ float4 sh[NPTS];           // 32 KB column array
    __shared__ float wsum[THREADS / 64];

    const int pair  = blockIdx.x;         // 0..63  (r*16 + i)
    const int chunk = blockIdx.y;         // 0..CHUNKS-1
    const int passB = blockIdx.z;         // 0: rows=target (cham_x), 1: rows=transformed (cham_y)
    const int i = pair & (IDIM - 1);
    const int tid = threadIdx.x;

    // ---- rotation matrix R = Rx(ax) @ Ry(ay) @ Rz(az), wave-uniform ----
    const float ax = rotv[pair * 3 + 0];
    const float ay = rotv[pair * 3 + 1];
    const float az = rotv[pair * 3 + 2];
    float sx, cx, sy, cy, sz, cz;
    sincosf(ax, &sx, &cx);
    sincosf(ay, &sy, &cy);
    sincosf(az, &sz, &cz);
    const float r00 = cy * cz,                 r01 = -cy * sz,                r02 = sy;
    const float r10 = cx * sz + sx * sy * cz,  r11 = cx * cz - sx * sy * sz,  r12 = -sx * cy;
    const float r20 = sx * sz - cx * sy * cz,  r21 = sx * cz + cx * sy * sz,  r22 = cx * cy;
    const float t0 = trav[pair * 3 + 0];
    const float t1 = trav[pair * 3 + 1];
    const float t2 = trav[pair * 3 + 2];
    const float s  = scal[pair];

    const float* __restrict__ srcp = src + (size_t)pair * NPTS * 3;
    const float* __restrict__ tgtp = tgt + (size_t)i    * NPTS * 3;

    // ---- stage column points into LDS as (-2v0, -2v1, -2v2, |v|^2) ----
    for (int idx = tid; idx < NPTS; idx += THREADS) {
        float v0, v1, v2;
        if (passB == 0) {
            // columns = transformed source points y
            const float p0 = srcp[idx * 3 + 0];
            const float p1 = srcp[idx * 3 + 1];
            const float p2 = srcp[idx * 3 + 2];
            v0 = s * (r00 * p0 + r01 * p1 + r02 * p2 + t0);
            v1 = s * (r10 * p0 + r11 * p1 + r12 * p2 + t1);
            v2 = s * (r20 * p0 + r21 * p1 + r22 * p2 + t2);
        } else {
            // columns = target points x
            v0 = tgtp[idx * 3 + 0];
            v1 = tgtp[idx * 3 + 1];
            v2 = tgtp[idx * 3 + 2];
        }
        sh[idx] = make_float4(-2.0f * v0, -2.0f * v1, -2.0f * v2,
                              v0 * v0 + v1 * v1 + v2 * v2);
    }
    __syncthreads();

    // ---- own rows (registers) ----
    float px[U], py[U], pz[U], p2[U], mn[U];
#pragma unroll
    for (int u = 0; u < U; ++u) {
        const int n = chunk * ROWS_PER_BLOCK + u * THREADS + tid;
        float q0, q1, q2;
        if (passB == 0) {
            q0 = tgtp[n * 3 + 0];
            q1 = tgtp[n * 3 + 1];
            q2 = tgtp[n * 3 + 2];
        } else {
            const float p0 = srcp[n * 3 + 0];
            const float p1 = srcp[n * 3 + 1];
            const float p2_ = srcp[n * 3 + 2];
            q0 = s * (r00 * p0 + r01 * p1 + r02 * p2_ + t0);
            q1 = s * (r10 * p0 + r11 * p1 + r12 * p2_ + t1);
            q2 = s * (r20 * p0 + r21 * p1 + r22 * p2_ + t2);
        }
        px[u] = q0; py[u] = q1; pz[u] = q2;
        p2[u] = q0 * q0 + q1 * q1 + q2 * q2;
        mn[u] = 3.4e38f;
    }

    // ---- inner loop: min over all columns of (v^2 - 2 p.v) ----
#pragma unroll 8
    for (int m = 0; m < NPTS; ++m) {
        const float4 c = sh[m];
#pragma unroll
        for (int u = 0; u < U; ++u) {
            const float g = fmaf(px[u], c.x, fmaf(py[u], c.y, fmaf(pz[u], c.z, c.w)));
            mn[u] = fminf(mn[u], g);
        }
    }

    float partial = 0.0f;
#pragma unroll
    for (int u = 0; u < U; ++u) partial += mn[u] + p2[u];

    // ---- block reduction: wave shuffle, then across waves ----
#pragma unroll
    for (int off = 32; off > 0; off >>= 1)
        partial += __shfl_down(partial, off, 64);
    if ((tid & 63) == 0) wsum[tid >> 6] = partial;
    __syncthreads();
    if (tid == 0) {
        float tot = 0.0f;
#pragma unroll
        for (int w = 0; w < THREADS / 64; ++w) tot += wsum[w];
        atomicAdd(&out[pair], tot * (1.0f / NPTS));
    }
}

extern "C" void kernel_launch(void* const* d_in, const int* in_sizes, int n_in,
                              void* d_out, int out_size, void* d_ws, size_t ws_size,
                              hipStream_t stream) {
    const float* src  = (const float*)d_in[0];  // source_points [4,16,2048,3]
    const float* tgt  = (const float*)d_in[1];  // target_points [16,2048,3]
    const float* rotv = (const float*)d_in[2];  // rotation [4,16,3]
    const float* trav = (const float*)d_in[3];  // translation [4,16,3]
    const float* scal = (const float*)d_in[4];  // scale [4,16]
    float* out = (float*)d_out;                 // [4,16]

    hipMemsetAsync(out, 0, RDIM * IDIM * sizeof(float), stream);

    dim3 grid(RDIM * IDIM, CHUNKS, 2);
    dim3 block(THREADS);
    chamfer_pass<<<grid, block, 0, stream>>>(src, tgt, rotv, trav, scal, out);
}

// Round 2
// 110.682 us; speedup vs baseline: 1.0027x; 1.0027x over previous
//
#include <hip/hip_runtime.h>
#include <math.h>

// Problem constants (from setup_inputs): R=4, I=16, N=2048.
#define RDIM 4
#define IDIM 16
#define NPTS 2048
#define THREADS 256
#define COLCHUNKS 8
#define COLS_PER_BLOCK (NPTS / COLCHUNKS)   // 256
#define U (NPTS / THREADS)                  // 8 rows per thread (whole row range per block)

// Workspace layout: part[pass][pair][colchunk][row] : 2*64*8*2048 floats = 8 MB
#define PART_IDX(passB, pair, cc, n) ((((size_t)(passB) * 64 + (pair)) * COLCHUNKS + (cc)) * NPTS + (n))

__device__ __forceinline__ void make_rot(const float* __restrict__ rotv, int pair,
                                         float& r00, float& r01, float& r02,
                                         float& r10, float& r11, float& r12,
                                         float& r20, float& r21, float& r22) {
    const float ax = rotv[pair * 3 + 0];
    const float ay = rotv[pair * 3 + 1];
    const float az = rotv[pair * 3 + 2];
    float sx, cx, sy, cy, sz, cz;
    sincosf(ax, &sx, &cx);
    sincosf(ay, &sy, &cy);
    sincosf(az, &sz, &cz);
    r00 = cy * cz;                r01 = -cy * sz;               r02 = sy;
    r10 = cx * sz + sx * sy * cz; r11 = cx * cz - sx * sy * sz; r12 = -sx * cy;
    r20 = sx * sz - cx * sy * cz; r21 = sx * cz + cx * sy * sz; r22 = cx * cy;
}

// Kernel 1: per (pair, colchunk, pass) block computes min over this chunk's
// columns for ALL 2048 rows (U=8 rows/thread -> each ds_read_b128 broadcast
// feeds 32 VALU ops, keeping LDS return-bandwidth well under the VALU time).
__global__ __launch_bounds__(THREADS, 4)
void chamfer_min(const float* __restrict__ src,   // [4,16,2048,3]
                 const float* __restrict__ tgt,   // [16,2048,3]
                 const float* __restrict__ rotv,  // [4,16,3]
                 const float* __restrict__ trav,  // [4,16,3]
                 const float* __restrict__ scal,  // [4,16]
                 float* __restrict__ part)        // ws, see PART_IDX
{
    __shared__ float4 sh[COLS_PER_BLOCK];         // 4 KB

    const int pair  = blockIdx.x;                 // 0..63
    const int cc    = blockIdx.y;                 // 0..COLCHUNKS-1
    const int passB = blockIdx.z;                 // 0: rows=target, cols=transformed; 1: swapped
    const int i   = pair & (IDIM - 1);
    const int tid = threadIdx.x;

    float r00, r01, r02, r10, r11, r12, r20, r21, r22;
    make_rot(rotv, pair, r00, r01, r02, r10, r11, r12, r20, r21, r22);
    const float t0 = trav[pair * 3 + 0];
    const float t1 = trav[pair * 3 + 1];
    const float t2 = trav[pair * 3 + 2];
    const float s  = scal[pair];

    const float* __restrict__ srcp = src + (size_t)pair * NPTS * 3;
    const float* __restrict__ tgtp = tgt + (size_t)i    * NPTS * 3;

    // ---- stage this chunk's columns as (-2v0, -2v1, -2v2, |v|^2) ----
    {
        const int m = cc * COLS_PER_BLOCK + tid;  // THREADS == COLS_PER_BLOCK
        float v0, v1, v2;
        if (passB == 0) {
            const float p0 = srcp[m * 3 + 0];
            const float p1 = srcp[m * 3 + 1];
            const float p2 = srcp[m * 3 + 2];
            v0 = s * (r00 * p0 + r01 * p1 + r02 * p2 + t0);
            v1 = s * (r10 * p0 + r11 * p1 + r12 * p2 + t1);
            v2 = s * (r20 * p0 + r21 * p1 + r22 * p2 + t2);
        } else {
            v0 = tgtp[m * 3 + 0];
            v1 = tgtp[m * 3 + 1];
            v2 = tgtp[m * 3 + 2];
        }
        sh[tid] = make_float4(-2.0f * v0, -2.0f * v1, -2.0f * v2,
                              v0 * v0 + v1 * v1 + v2 * v2);
    }
    __syncthreads();

    // ---- own rows (registers): U=8 rows per thread ----
    float px[U], py[U], pz[U], mn[U];
#pragma unroll
    for (int u = 0; u < U; ++u) {
        const int n = u * THREADS + tid;
        float q0, q1, q2;
        if (passB == 0) {
            q0 = tgtp[n * 3 + 0];
            q1 = tgtp[n * 3 + 1];
            q2 = tgtp[n * 3 + 2];
        } else {
            const float p0 = srcp[n * 3 + 0];
            const float p1 = srcp[n * 3 + 1];
            const float p2 = srcp[n * 3 + 2];
            q0 = s * (r00 * p0 + r01 * p1 + r02 * p2 + t0);
            q1 = s * (r10 * p0 + r11 * p1 + r12 * p2 + t1);
            q2 = s * (r20 * p0 + r21 * p1 + r22 * p2 + t2);
        }
        px[u] = q0; py[u] = q1; pz[u] = q2;
        mn[u] = 3.4e38f;
    }

    // ---- inner loop: min over chunk columns of (v^2 - 2 p.v) ----
#pragma unroll 4
    for (int m = 0; m < COLS_PER_BLOCK; ++m) {
        const float4 c = sh[m];
#pragma unroll
        for (int u = 0; u < U; ++u) {
            const float g = fmaf(px[u], c.x, fmaf(py[u], c.y, fmaf(pz[u], c.z, c.w)));
            mn[u] = fminf(mn[u], g);
        }
    }

    // ---- write per-chunk partial mins (coalesced) ----
#pragma unroll
    for (int u = 0; u < U; ++u)
        part[PART_IDX(passB, pair, cc, u * THREADS + tid)] = mn[u];
}

// Kernel 2: per (pair, pass) block: min across colchunks, add |row|^2,
// mean over rows, atomicAdd into out[pair].
__global__ __launch_bounds__(THREADS, 4)
void chamfer_reduce(const float* __restrict__ src,
                    const float* __restrict__ tgt,
                    const float* __restrict__ rotv,
                    const float* __restrict__ trav,
                    const float* __restrict__ scal,
                    const float* __restrict__ part,
                    float* __restrict__ out)      // [4,16]
{
    __shared__ float wsum[THREADS / 64];

    const int pair  = blockIdx.x;
    const int passB = blockIdx.y;
    const int i   = pair & (IDIM - 1);
    const int tid = threadIdx.x;

    float r00, r01, r02, r10, r11, r12, r20, r21, r22;
    make_rot(rotv, pair, r00, r01, r02, r10, r11, r12, r20, r21, r22);
    const float t0 = trav[pair * 3 + 0];
    const float t1 = trav[pair * 3 + 1];
    const float t2 = trav[pair * 3 + 2];
    const float s  = scal[pair];

    const float* __restrict__ srcp = src + (size_t)pair * NPTS * 3;
    const float* __restrict__ tgtp = tgt + (size_t)i    * NPTS * 3;
    const size_t base = PART_IDX(passB, pair, 0, 0);

    float sum = 0.0f;
#pragma unroll
    for (int u = 0; u < U; ++u) {
        const int n = u * THREADS + tid;
        float m = part[base + n];
#pragma unroll
        for (int c = 1; c < COLCHUNKS; ++c)
            m = fminf(m, part[base + (size_t)c * NPTS + n]);
        float q0, q1, q2;
        if (passB == 0) {
            q0 = tgtp[n * 3 + 0];
            q1 = tgtp[n * 3 + 1];
            q2 = tgtp[n * 3 + 2];
        } else {
            const float p0 = srcp[n * 3 + 0];
            const float p1 = srcp[n * 3 + 1];
            const float p2 = srcp[n * 3 + 2];
            q0 = s * (r00 * p0 + r01 * p1 + r02 * p2 + t0);
            q1 = s * (r10 * p0 + r11 * p1 + r12 * p2 + t1);
            q2 = s * (r20 * p0 + r21 * p1 + r22 * p2 + t2);
        }
        sum += m + (q0 * q0 + q1 * q1 + q2 * q2);
    }

#pragma unroll
    for (int off = 32; off > 0; off >>= 1)
        sum += __shfl_down(sum, off, 64);
    if ((tid & 63) == 0) wsum[tid >> 6] = sum;
    __syncthreads();
    if (tid == 0) {
        float tot = 0.0f;
#pragma unroll
        for (int w = 0; w < THREADS / 64; ++w) tot += wsum[w];
        atomicAdd(&out[pair], tot * (1.0f / NPTS));
    }
}

extern "C" void kernel_launch(void* const* d_in, const int* in_sizes, int n_in,
                              void* d_out, int out_size, void* d_ws, size_t ws_size,
                              hipStream_t stream) {
    const float* src  = (const float*)d_in[0];  // source_points [4,16,2048,3]
    const float* tgt  = (const float*)d_in[1];  // target_points [16,2048,3]
    const float* rotv = (const float*)d_in[2];  // rotation [4,16,3]
    const float* trav = (const float*)d_in[3];  // translation [4,16,3]
    const float* scal = (const float*)d_in[4];  // scale [4,16]
    float* out  = (float*)d_out;                // [4,16]
    float* part = (float*)d_ws;                 // 8 MB partial mins

    hipMemsetAsync(out, 0, RDIM * IDIM * sizeof(float), stream);

    dim3 grid1(RDIM * IDIM, COLCHUNKS, 2);
    chamfer_min<<<grid1, THREADS, 0, stream>>>(src, tgt, rotv, trav, scal, part);

    dim3 grid2(RDIM * IDIM, 2);
    chamfer_reduce<<<grid2, THREADS, 0, stream>>>(src, tgt, rotv, trav, scal, part, out);
}